// Round 16
// baseline (775.704 us; speedup 1.0000x reference)
//
#include <hip/hip_runtime.h>

#define TT 1024
#define SSZ 1024
#define DD 64
#define BHN 64
#define BSZN 4
#define EEN 1024
#define EPSF 1e-6f

using f32x2 = __attribute__((ext_vector_type(2))) float;
using f32x4 = __attribute__((ext_vector_type(4))) float;
using i32x2 = __attribute__((ext_vector_type(2))) int;
using i32x4 = __attribute__((ext_vector_type(4))) int;
using s16x8 = __attribute__((ext_vector_type(8))) short;

// static buffers (avoid ws_size assumptions)
__device__ unsigned short g_Qb[(size_t)BHN * TT * SSZ];  // bf16 p_choose, row-major [bh][t][s]
__device__ unsigned short g_Pb[(size_t)BHN * TT * SSZ];  // bf16 alpha, k-blocked [bh*32+sb][t][32]
__device__ unsigned short g_Vt[(size_t)BHN * DD * SSZ];  // bf16 V^T, k-blocked [bh*32+sb][d][32]
__device__ unsigned short g_Wb[(size_t)EEN * EEN];       // bf16 W row-major [n][k]
__device__ unsigned short g_Xb[(size_t)TT * BSZN * EEN]; // bf16 X, k-blocked [eb][m][32]

// ---------------- helpers ----------------
template<int CTRL, int RM>
__device__ __forceinline__ float f_dpp(float x, float ident) {
  return __builtin_bit_cast(float,
      __builtin_amdgcn_update_dpp(__builtin_bit_cast(int, ident),
                                  __builtin_bit_cast(int, x),
                                  CTRL, RM, 0xF, false));
}

__device__ __forceinline__ float wscan_add(float x) {
  x += f_dpp<0x111, 0xF>(x, 0.0f);
  x += f_dpp<0x112, 0xF>(x, 0.0f);
  x += f_dpp<0x114, 0xF>(x, 0.0f);
  x += f_dpp<0x118, 0xF>(x, 0.0f);
  x += f_dpp<0x142, 0xA>(x, 0.0f);
  x += f_dpp<0x143, 0xC>(x, 0.0f);
  return x;
}

__device__ __forceinline__ float wave_shr1(float x, float ident) {
  return f_dpp<0x138, 0xF>(x, ident);
}

__device__ __forceinline__ int aload1(const unsigned short* p) {
  int r;
  asm volatile("global_load_dword %0, %1, off" : "=v"(r) : "v"(p));
  return r;
}
__device__ __forceinline__ void astore2f(float* p, f32x2 v) {
  asm volatile("global_store_dwordx2 %0, %1, off" :: "v"(p), "v"(v) : "memory");
}
__device__ __forceinline__ void astore1(unsigned short* p, int v) {
  asm volatile("global_store_dword %0, %1, off" :: "v"(p), "v"(v) : "memory");
}

__device__ __forceinline__ int cvt_pk(float lo, float hi) {
  int r;
  asm("v_cvt_pk_bf16_f32 %0, %1, %2" : "=v"(r) : "v"(lo), "v"(hi));
  return r;
}
__device__ __forceinline__ unsigned short bfr(float x) {  // scalar RTNE bf16
  unsigned u = __builtin_bit_cast(unsigned, x);
  u += 0x7fffu + ((u >> 16) & 1u);
  return (unsigned short)(u >> 16);
}
__device__ __forceinline__ float bfl(int u) {  // low bf16 -> f32
  return __builtin_bit_cast(float, u << 16);
}
__device__ __forceinline__ float bfh(int u) {  // high bf16 -> f32
  return __builtin_bit_cast(float, (int)((unsigned)u & 0xffff0000u));
}
__device__ __forceinline__ s16x8 pack8p(const float* p) {  // 8 consecutive f32 -> bf16x8
  f32x4 a = *(const f32x4*)p;
  f32x4 b = *(const f32x4*)(p + 4);
  i32x4 r;
  r[0] = cvt_pk(a[0], a[1]); r[1] = cvt_pk(a[2], a[3]);
  r[2] = cvt_pk(b[0], b[1]); r[3] = cvt_pk(b[2], b[3]);
  return __builtin_bit_cast(s16x8, r);
}
__device__ __forceinline__ s16x8 pack8f(float v0, float v1, float v2, float v3,
                                        float v4, float v5, float v6, float v7) {
  i32x4 r;
  r[0] = cvt_pk(v0, v1); r[1] = cvt_pk(v2, v3);
  r[2] = cvt_pk(v4, v5); r[3] = cvt_pk(v6, v7);
  return __builtin_bit_cast(s16x8, r);
}

// ---------------- prep: W -> bf16 ----------------
__global__ __launch_bounds__(256) void k_prep_w(const float* __restrict__ W) {
  const size_t idx = ((size_t)blockIdx.x * 256 + threadIdx.x) * 8;
  *(s16x8*)(g_Wb + idx) = pack8p(W + idx);
}

// ---------------- prep: V -> bf16 k-blocked V^T [bh*32+sb][d][32] ----------------
__global__ __launch_bounds__(256) void k_prep_v(const float* __restrict__ V) {
  __shared__ float tile[64][65];
  const int tid = threadIdx.x;
  const int bh = blockIdx.x >> 4;
  const int s0 = (blockIdx.x & 15) << 6;
  {
    const int r = tid >> 2, cq = (tid & 3) << 4;
    const float* src = V + ((size_t)bh * SSZ + s0 + r) * DD + cq;
    *(float4*)&tile[r][cq + 0]  = *(const float4*)(src + 0);
    *(float4*)&tile[r][cq + 4]  = *(const float4*)(src + 4);
    *(float4*)&tile[r][cq + 8]  = *(const float4*)(src + 8);
    *(float4*)&tile[r][cq + 12] = *(const float4*)(src + 12);
  }
  __syncthreads();
  {
    const int d = tid >> 2, sq = (tid & 3) << 4;
    const int s1 = s0 + sq, s2 = s1 + 8;
    unsigned short* d0 = g_Vt + ((size_t)(bh * 32 + (s1 >> 5)) * DD + d) * 32 + (s1 & 31);
    unsigned short* d1 = g_Vt + ((size_t)(bh * 32 + (s2 >> 5)) * DD + d) * 32 + (s2 & 31);
    *(s16x8*)d0 = pack8f(tile[sq + 0][d], tile[sq + 1][d], tile[sq + 2][d], tile[sq + 3][d],
                         tile[sq + 4][d], tile[sq + 5][d], tile[sq + 6][d], tile[sq + 7][d]);
    *(s16x8*)d1 = pack8f(tile[sq + 8][d], tile[sq + 9][d], tile[sq + 10][d], tile[sq + 11][d],
                         tile[sq + 12][d], tile[sq + 13][d], tile[sq + 14][d], tile[sq + 15][d]);
  }
}

// ---------------- K1: p = sigmoid(Q K^T + bias) via bf16 MFMA -> g_Qb (bf16) ----------------
__global__ __launch_bounds__(256) void k_energy(const float* __restrict__ Q,
                                                const float* __restrict__ Kp,
                                                const float* __restrict__ eb) {
  const int tid = threadIdx.x, w = tid >> 6, l = tid & 63;
  const int rl = l & 15, kg = l >> 4;
  const int bh = blockIdx.x >> 6;
  const int tile = blockIdx.x & 63;
  const int m0 = (tile >> 2) << 6;
  const int n0 = (((tile & 3) << 2) + w) << 6;
  const float* qb = Q + (size_t)bh * TT * DD;
  const float* kb = Kp + (size_t)bh * SSZ * DD;

  f32x4 acc[4][4];
#pragma unroll
  for (int i = 0; i < 4; ++i)
#pragma unroll
    for (int j = 0; j < 4; ++j) acc[i][j] = (f32x4)0.0f;

#pragma unroll
  for (int ks = 0; ks < 2; ++ks) {
    const int kof = (ks << 5) + (kg << 3);
    s16x8 af[4], bf[4];
#pragma unroll
    for (int fi = 0; fi < 4; ++fi)
      af[fi] = pack8p(qb + (size_t)(m0 + fi * 16 + rl) * DD + kof);
#pragma unroll
    for (int fj = 0; fj < 4; ++fj)
      bf[fj] = pack8p(kb + (size_t)(n0 + fj * 16 + rl) * DD + kof);
#pragma unroll
    for (int fi = 0; fi < 4; ++fi)
#pragma unroll
      for (int fj = 0; fj < 4; ++fj)
        acc[fi][fj] = __builtin_amdgcn_mfma_f32_16x16x32_bf16(af[fi], bf[fj], acc[fi][fj], 0, 0, 0);
  }

  const float bias = eb[0];
  unsigned short* pb = g_Qb + (size_t)bh * TT * SSZ;
#pragma unroll
  for (int fi = 0; fi < 4; ++fi)
#pragma unroll
    for (int r = 0; r < 4; ++r) {
      const size_t rowoff = (size_t)(m0 + fi * 16 + (kg << 2) + r) * SSZ;
#pragma unroll
      for (int fj = 0; fj < 4; ++fj) {
        float x = acc[fi][fj][r] + bias;
        float s = __builtin_amdgcn_rcpf(1.0f + __expf(-x));
        pb[rowoff + n0 + fj * 16 + rl] = bfr(s);
      }
    }
}

// ---------------- K2: 8-wave s-split scan (2 elems/lane; proven STEP protocol) ----------------
#define STEP(T, QS) do {                                                       \
  const int t_ = (T);                                                          \
  asm volatile("s_waitcnt vmcnt(8)" ::: "memory");                             \
  __builtin_amdgcn_sched_barrier(0);                                           \
  float fn0 = 1.0f - bfl(QS);                                                  \
  float fn1 = 1.0f - bfh(QS);                                                  \
  { int rr = t_ + 5; if (rr > TT - 1) rr = TT - 1;                             \
    QS = aload1(gqe + (size_t)rr * SSZ); }                                     \
  float ln0 = fn0, ln1 = ln0 * fn1;                                            \
  float An0 = ln1;                                                             \
  float An1 = An0 * f_dpp<0x111, 0xF>(An0, 1.0f);                              \
  float An2 = An1 * f_dpp<0x112, 0xF>(An1, 1.0f);                              \
  float An3 = An2 * f_dpp<0x114, 0xF>(An2, 1.0f);                              \
  float An4 = An3 * f_dpp<0x118, 0xF>(An3, 1.0f);                              \
  float An5 = An4 * f_dpp<0x142, 0xA>(An4, 1.0f);                              \
  float An6 = An5 * f_dpp<0x143, 0xC>(An5, 1.0f);                              \
  float wEn = wave_shr1(An6, 1.0f);                                            \
  float bb0 = fminf(c0  * prev0, prev0);                                       \
  float bb1 = fminf(cl0 * prev1, prev1);                                       \
  float Blo1 = fmaf(fc0, bb0, bb1);                                            \
  float B_ = fc1 * Blo1;                                                       \
  B_ = fmaf(As0, f_dpp<0x111, 0xF>(B_, 0.0f), B_);                             \
  B_ = fmaf(As1, f_dpp<0x112, 0xF>(B_, 0.0f), B_);                             \
  B_ = fmaf(As2, f_dpp<0x114, 0xF>(B_, 0.0f), B_);                             \
  B_ = fmaf(As3, f_dpp<0x118, 0xF>(B_, 0.0f), B_);                             \
  B_ = fmaf(As4, f_dpp<0x142, 0xA>(B_, 0.0f), B_);                             \
  float Bfull = fmaf(As5, f_dpp<0x143, 0xC>(B_, 0.0f), B_);                    \
  float wB = wave_shr1(Bfull, 0.0f);                                           \
  if (lane == 63) ldsAB[t_ & 1][w] = make_float2(An6, Bfull);                  \
  asm volatile("s_waitcnt lgkmcnt(0)" ::: "memory");                           \
  __builtin_amdgcn_s_barrier();                                                \
  __builtin_amdgcn_sched_barrier(0);                                           \
  float2 ab0 = ldsAB[t_ & 1][0];                                               \
  float2 ab1 = ldsAB[t_ & 1][1];                                               \
  float2 ab2 = ldsAB[t_ & 1][2];                                               \
  float2 ab3 = ldsAB[t_ & 1][3];                                               \
  float2 ab4 = ldsAB[t_ & 1][4];                                               \
  float2 ab5 = ldsAB[t_ & 1][5];                                               \
  float2 ab6 = ldsAB[t_ & 1][6];                                               \
  float e = ab0.y;                                                             \
  float Ew = 0.0f;                                                             \
  if (w == 1) Ew = e;                                                          \
  e = fmaf(Ag1, e, ab1.y); if (w == 2) Ew = e;                                 \
  e = fmaf(Ag2, e, ab2.y); if (w == 3) Ew = e;                                 \
  e = fmaf(Ag3, e, ab3.y); if (w == 4) Ew = e;                                 \
  e = fmaf(Ag4, e, ab4.y); if (w == 5) Ew = e;                                 \
  e = fmaf(Ag5, e, ab5.y); if (w == 6) Ew = e;                                 \
  e = fmaf(Ag6, e, ab6.y); if (w == 7) Ew = e;                                 \
  float El = fmaf(wE, Ew, wB);                                                 \
  float D0 = bb0 + El;                                                         \
  float D1 = fmaf(lc0, El, Blo1);                                              \
  float a0 = fminf(fmaf(-fc0, D0, D0), 1.0f);                                  \
  float a1 = fminf(fmaf(-fc1, D1, D1), 1.0f);                                  \
  prev0 = a0; prev1 = a1;                                                      \
  if (tid != 511) {                                                            \
    f32x2 av; av[0] = a0; av[1] = a1;                                          \
    astore2f(gq + (size_t)t_ * SSZ, av);                                       \
    astore1(gpb + (size_t)t_ * 32, cvt_pk(a0, a1));                            \
  }                                                                            \
  float wsum = wscan_add(a0 + a1);                                             \
  if (lane == 63 && w < 7) ldsS[t_ & 1][w] = wsum;                             \
  if (tid == 511) {                                                            \
    if (t_ > 0) {                                                              \
      const int p_ = (t_ - 1) & 1;                                             \
      float tot = ((ldsS[p_][0] + ldsS[p_][1]) + (ldsS[p_][2] + ldsS[p_][3]))  \
                + ((ldsS[p_][4] + ldsS[p_][5]) + ldsS[p_][6]) + wsum_prev;     \
      float rest = tot - pend1;                                                \
      pend1 = 1.0f - fminf(fmaxf(rest, 0.0f), 1.0f);                           \
      f32x2 pv; pv[0] = pend0; pv[1] = pend1;                                  \
      astore2f(gq + (size_t)(t_ - 1) * SSZ, pv);                               \
      astore1(gpb + (size_t)(t_ - 1) * 32, cvt_pk(pend0, pend1));              \
    }                                                                          \
    pend0 = a0; pend1 = a1; wsum_prev = wsum;                                  \
  }                                                                            \
  fc0 = fn0; fc1 = fn1; lc0 = ln0;                                             \
  As0 = An0; As1 = An1; As2 = An2; As3 = An3; As4 = An4; As5 = An5;            \
  wE = wEn;                                                                    \
  Ag1 = ab1.x; Ag2 = ab2.x; Ag3 = ab3.x;                                       \
  Ag4 = ab4.x; Ag5 = ab5.x; Ag6 = ab6.x;                                       \
  float p1 = ab0.x;                                                            \
  float p2 = p1 * ab1.x;                                                       \
  float p3 = p2 * ab2.x;                                                       \
  float p4 = p3 * ab3.x;                                                       \
  float p5 = p4 * ab4.x;                                                       \
  float p6 = p5 * ab5.x;                                                       \
  float p7 = p6 * ab6.x;                                                       \
  float Pw_ = 1.0f;                                                            \
  if (w == 1) Pw_ = p1; else if (w == 2) Pw_ = p2; else if (w == 3) Pw_ = p3;  \
  else if (w == 4) Pw_ = p4; else if (w == 5) Pw_ = p5;                        \
  else if (w == 6) Pw_ = p6; else if (w == 7) Pw_ = p7;                        \
  c0 = (Pw_ * 1e6f) * wEn;                                                     \
  cl0 = c0 * ln0;                                                              \
} while (0)

__global__ __launch_bounds__(512, 1) void k_scan(float* __restrict__ A) {
  const int b = blockIdx.x;
  const int tid = threadIdx.x;
  const int w = tid >> 6;
  const int lane = tid & 63;
  __shared__ float2 ldsAB[2][8];
  __shared__ float ldsS[2][8];

  // lane owns s = w*128 + lane*2 (2 elems)
  float* gq = A + (size_t)b * TT * SSZ + ((size_t)w << 7) + ((size_t)lane << 1);
  const unsigned short* gqe = g_Qb + (size_t)b * TT * SSZ + ((size_t)w << 7) + ((size_t)lane << 1);
  const int sb = (w << 2) + (lane >> 4);
  unsigned short* gpb = g_Pb + ((size_t)(b * 32 + sb) * TT) * 32 + ((lane & 15) << 1);

  // ring: slot k holds row r with r&3==k
  int q0 = aload1(gqe + (size_t)0 * SSZ);
  int q1 = aload1(gqe + (size_t)1 * SSZ);
  int q2 = aload1(gqe + (size_t)2 * SSZ);
  int q3 = aload1(gqe + (size_t)3 * SSZ);
  asm volatile("s_waitcnt vmcnt(0)" ::: "memory");
  __builtin_amdgcn_sched_barrier(0);

  // row-0 state
  float fc0 = 1.0f - bfl(q0);
  float fc1 = 1.0f - bfh(q0);
  q0 = aload1(gqe + (size_t)4 * SSZ);
  float lc0 = fc0;
  float lc1 = lc0 * fc1;
  float As0 = lc1;
  float As1 = As0 * f_dpp<0x111, 0xF>(As0, 1.0f);
  float As2 = As1 * f_dpp<0x112, 0xF>(As1, 1.0f);
  float As3 = As2 * f_dpp<0x114, 0xF>(As2, 1.0f);
  float As4 = As3 * f_dpp<0x118, 0xF>(As3, 1.0f);
  float As5 = As4 * f_dpp<0x142, 0xA>(As4, 1.0f);
  float A6  = As5 * f_dpp<0x143, 0xC>(As5, 1.0f);
  float wE = wave_shr1(A6, 1.0f);
  if (lane == 63) ldsAB[1][w] = make_float2(A6, 0.0f);
  asm volatile("s_waitcnt lgkmcnt(0)" ::: "memory");
  __builtin_amdgcn_s_barrier();
  __builtin_amdgcn_sched_barrier(0);
  float2 pb0 = ldsAB[1][0], pb1 = ldsAB[1][1], pb2 = ldsAB[1][2];
  float2 pb3 = ldsAB[1][3], pb4 = ldsAB[1][4], pb5 = ldsAB[1][5];
  float2 pb6 = ldsAB[1][6];
  float Ag1 = pb1.x, Ag2 = pb2.x, Ag3 = pb3.x;
  float Ag4 = pb4.x, Ag5 = pb5.x, Ag6 = pb6.x;
  {
  }
  float p1 = pb0.x;
  float p2 = p1 * pb1.x;
  float p3 = p2 * pb2.x;
  float p4 = p3 * pb3.x;
  float p5 = p4 * pb4.x;
  float p6 = p5 * pb5.x;
  float p7 = p6 * pb6.x;
  float Pw = 1.0f;
  if (w == 1) Pw = p1; else if (w == 2) Pw = p2; else if (w == 3) Pw = p3;
  else if (w == 4) Pw = p4; else if (w == 5) Pw = p5;
  else if (w == 6) Pw = p6; else if (w == 7) Pw = p7;
  float c0 = (Pw * 1e6f) * wE;
  float cl0 = c0 * lc0;

  float prev0 = (tid == 0) ? 1.0f : 0.0f;
  float prev1 = 0.0f;
  float pend0 = 0.0f, pend1 = 0.0f;
  float wsum_prev = 0.0f;

  for (int t0 = 0; t0 < TT; t0 += 4) {
    STEP(t0 + 0, q1);
    STEP(t0 + 1, q2);
    STEP(t0 + 2, q3);
    STEP(t0 + 3, q0);
  }

  asm volatile("s_waitcnt lgkmcnt(0)" ::: "memory");
  __builtin_amdgcn_s_barrier();
  __builtin_amdgcn_sched_barrier(0);
  if (tid == 511) {
    const int p_ = (TT - 1) & 1;
    float tot = ((ldsS[p_][0] + ldsS[p_][1]) + (ldsS[p_][2] + ldsS[p_][3]))
              + ((ldsS[p_][4] + ldsS[p_][5]) + ldsS[p_][6]) + wsum_prev;
    float rest = tot - pend1;
    pend1 = 1.0f - fminf(fmaxf(rest, 0.0f), 1.0f);
    f32x2 pv; pv[0] = pend0; pv[1] = pend1;
    astore2f(gq + (size_t)(TT - 1) * SSZ, pv);
    astore1(gpb + (size_t)(TT - 1) * 32, cvt_pk(pend0, pend1));
  }
}

// ---------------- K3: X = alpha_bf16 @ V^T_bf16 via MFMA -> g_Xb (k-blocked) ----------------
__global__ __launch_bounds__(256) void k_av() {
  const int tid = threadIdx.x, w = tid >> 6, l = tid & 63;
  const int rl = l & 15, kg = l >> 4;
  const int gw = blockIdx.x * 4 + w;
  const int bh = gw >> 6;
  const int t0 = (gw & 63) << 4;

  // k-blocked alpha: slot j of lane (rl,kg) at kk -> alpha[t0+rl][kk*32+kg*8+j]
  const unsigned short* ab = g_Pb + ((size_t)(bh * 32) * TT + (t0 + rl)) * 32 + (kg << 3);
  // k-blocked V^T: lane (rl,kg), fj, kk -> V^T[fj*16+rl][kk*32+kg*8+j]
  const unsigned short* vb = g_Vt + ((size_t)(bh * 32) * DD + rl) * 32 + (kg << 3);

  f32x4 acc[4];
#pragma unroll
  for (int j = 0; j < 4; ++j) acc[j] = (f32x4)0.0f;

  for (int kk = 0; kk < 32; ++kk) {
    s16x8 a = *(const s16x8*)(ab + (size_t)kk * TT * 32);
#pragma unroll
    for (int fj = 0; fj < 4; ++fj) {
      s16x8 b = *(const s16x8*)(vb + ((size_t)kk * DD + fj * 16) * 32);
      acc[fj] = __builtin_amdgcn_mfma_f32_16x16x32_bf16(a, b, acc[fj], 0, 0, 0);
    }
  }

  // store into k-blocked g_Xb: element (e, m) at ((e>>5)*4096 + m)*32 + (e&31)
  const int bz = bh >> 4, hh = bh & 15;
#pragma unroll
  for (int fj = 0; fj < 4; ++fj) {
    const int e = hh * DD + fj * 16 + rl;
    const size_t ebase = ((size_t)(e >> 5) * (TT * BSZN)) * 32 + (e & 31);
#pragma unroll
    for (int r = 0; r < 4; ++r) {
      const int m = (t0 + (kg << 2) + r) * BSZN + bz;
      g_Xb[ebase + (size_t)m * 32] = bfr(acc[fj][r]);
    }
  }
}

// ---------------- K4: Out = X_bf16 @ W_bf16^T + b via MFMA (k-blocked X loads) ----------------
__global__ __launch_bounds__(256) void k_out(const float* __restrict__ Bb,
                                             float* __restrict__ Out) {
  const int tid = threadIdx.x, w = tid >> 6, l = tid & 63;
  const int rl = l & 15, kg = l >> 4;
  const int gw = blockIdx.x * 4 + w;
  const int m0 = (gw >> 4) << 4;
  const int n0 = (gw & 15) << 6;

  // k-blocked X: slot j at kk -> X[m0+rl][kk*32+kg*8+j]
  const unsigned short* xb = g_Xb + (size_t)(m0 + rl) * 32 + (kg << 3);

  f32x4 acc[4];
#pragma unroll
  for (int j = 0; j < 4; ++j) acc[j] = (f32x4)0.0f;

  for (int kk = 0; kk < 32; ++kk) {
    s16x8 a = *(const s16x8*)(xb + (size_t)kk * (TT * BSZN) * 32);
    const int kof = (kk << 5) + (kg << 3);
#pragma unroll
    for (int fj = 0; fj < 4; ++fj) {
      s16x8 b = *(const s16x8*)(g_Wb + (size_t)(n0 + fj * 16 + rl) * EEN + kof);
      acc[fj] = __builtin_amdgcn_mfma_f32_16x16x32_bf16(a, b, acc[fj], 0, 0, 0);
    }
  }

#pragma unroll
  for (int fj = 0; fj < 4; ++fj) {
    const float bias = Bb[n0 + fj * 16 + rl];
#pragma unroll
    for (int r = 0; r < 4; ++r) {
      const int m = m0 + (kg << 2) + r;
      Out[(size_t)m * EEN + n0 + fj * 16 + rl] = acc[fj][r] + bias;
    }
  }
}

extern "C" void kernel_launch(void* const* d_in, const int* in_sizes, int n_in,
                              void* d_out, int out_size, void* d_ws, size_t ws_size,
                              hipStream_t stream) {
  const float* Q  = (const float*)d_in[0];
  const float* K  = (const float*)d_in[1];
  const float* V  = (const float*)d_in[2];
  const float* W  = (const float*)d_in[3];
  const float* Bb = (const float*)d_in[4];
  const float* eb = (const float*)d_in[5];
  float* Out = (float*)d_out;
  float* Alpha = Out + (size_t)TT * BSZN * EEN;  // alpha f32 output region

  k_prep_w<<<dim3(512), dim3(256), 0, stream>>>(W);
  k_prep_v<<<dim3(BHN * 16), dim3(256), 0, stream>>>(V);
  k_energy<<<dim3(BHN * 64), dim3(256), 0, stream>>>(Q, K, eb);
  k_scan<<<dim3(BHN), dim3(512), 0, stream>>>(Alpha);
  k_av<<<dim3(1024), dim3(256), 0, stream>>>();
  k_out<<<dim3(1024), dim3(256), 0, stream>>>(Bb, Out);
}

// Round 18
// 672.897 us; speedup vs baseline: 1.1528x; 1.1528x over previous
//
#include <hip/hip_runtime.h>

#define TT 1024
#define SSZ 1024
#define DD 64
#define BHN 64
#define BSZN 4
#define EEN 1024
#define EPSF 1e-6f

using f32x4 = __attribute__((ext_vector_type(4))) float;
using i32x2 = __attribute__((ext_vector_type(2))) int;
using i32x4 = __attribute__((ext_vector_type(4))) int;
using s16x8 = __attribute__((ext_vector_type(8))) short;

// static buffers (avoid ws_size assumptions)
__device__ unsigned short g_Qb[(size_t)BHN * TT * SSZ];  // bf16 p_choose, row-major [bh][t][s]
__device__ unsigned short g_Pb[(size_t)BHN * TT * SSZ];  // bf16 alpha, k-blocked [bh*32+sb][t][32]
__device__ unsigned short g_Vt[(size_t)BHN * DD * SSZ];  // bf16 V^T, k-blocked [bh*32+sb][d][32]
__device__ unsigned short g_Wb[(size_t)EEN * EEN];       // bf16 W, k-blocked [kb][n][32]
__device__ unsigned short g_Xb[(size_t)TT * BSZN * EEN]; // bf16 X, k-blocked [eb][m][32]

// ---------------- helpers ----------------
template<int CTRL, int RM>
__device__ __forceinline__ float f_dpp(float x, float ident) {
  return __builtin_bit_cast(float,
      __builtin_amdgcn_update_dpp(__builtin_bit_cast(int, ident),
                                  __builtin_bit_cast(int, x),
                                  CTRL, RM, 0xF, false));
}

__device__ __forceinline__ float wscan_add(float x) {
  x += f_dpp<0x111, 0xF>(x, 0.0f);
  x += f_dpp<0x112, 0xF>(x, 0.0f);
  x += f_dpp<0x114, 0xF>(x, 0.0f);
  x += f_dpp<0x118, 0xF>(x, 0.0f);
  x += f_dpp<0x142, 0xA>(x, 0.0f);
  x += f_dpp<0x143, 0xC>(x, 0.0f);
  return x;
}

__device__ __forceinline__ float wave_shr1(float x, float ident) {
  return f_dpp<0x138, 0xF>(x, ident);
}

__device__ __forceinline__ i32x2 aload2(const unsigned short* p) {
  i32x2 r;
  asm volatile("global_load_dwordx2 %0, %1, off" : "=v"(r) : "v"(p));
  return r;
}
__device__ __forceinline__ void astore(float* p, f32x4 v) {
  asm volatile("global_store_dwordx4 %0, %1, off" :: "v"(p), "v"(v) : "memory");
}
__device__ __forceinline__ void astore2(unsigned short* p, i32x2 v) {
  asm volatile("global_store_dwordx2 %0, %1, off" :: "v"(p), "v"(v) : "memory");
}

__device__ __forceinline__ int cvt_pk(float lo, float hi) {
  int r;
  asm("v_cvt_pk_bf16_f32 %0, %1, %2" : "=v"(r) : "v"(lo), "v"(hi));
  return r;
}
__device__ __forceinline__ unsigned short bfr(float x) {  // scalar RTNE bf16
  unsigned u = __builtin_bit_cast(unsigned, x);
  u += 0x7fffu + ((u >> 16) & 1u);
  return (unsigned short)(u >> 16);
}
__device__ __forceinline__ float bfl(int u) {  // low bf16 -> f32
  return __builtin_bit_cast(float, u << 16);
}
__device__ __forceinline__ float bfh(int u) {  // high bf16 -> f32
  return __builtin_bit_cast(float, (int)((unsigned)u & 0xffff0000u));
}
__device__ __forceinline__ s16x8 pack8p(const float* p) {  // 8 consecutive f32 -> bf16x8
  f32x4 a = *(const f32x4*)p;
  f32x4 b = *(const f32x4*)(p + 4);
  i32x4 r;
  r[0] = cvt_pk(a[0], a[1]); r[1] = cvt_pk(a[2], a[3]);
  r[2] = cvt_pk(b[0], b[1]); r[3] = cvt_pk(b[2], b[3]);
  return __builtin_bit_cast(s16x8, r);
}
__device__ __forceinline__ s16x8 pack8f(float v0, float v1, float v2, float v3,
                                        float v4, float v5, float v6, float v7) {
  i32x4 r;
  r[0] = cvt_pk(v0, v1); r[1] = cvt_pk(v2, v3);
  r[2] = cvt_pk(v4, v5); r[3] = cvt_pk(v6, v7);
  return __builtin_bit_cast(s16x8, r);
}

// ---------------- prep: W -> bf16, k-blocked [kb][n][32] ----------------
// element W[n][k] -> g_Wb[((k>>5)*EEN + n)*32 + (k&31)]; thread's 8 k's share one block.
__global__ __launch_bounds__(256) void k_prep_w(const float* __restrict__ W) {
  const size_t idx = ((size_t)blockIdx.x * 256 + threadIdx.x) * 8;
  const int n = (int)(idx >> 10);
  const int k0 = (int)(idx & 1023);
  unsigned short* dst = g_Wb + ((size_t)(k0 >> 5) * EEN + n) * 32 + (k0 & 31);
  *(s16x8*)dst = pack8p(W + idx);
}

// ---------------- prep: V -> bf16 k-blocked V^T [bh*32+sb][d][32] ----------------
__global__ __launch_bounds__(256) void k_prep_v(const float* __restrict__ V) {
  __shared__ float tile[64][65];
  const int tid = threadIdx.x;
  const int bh = blockIdx.x >> 4;
  const int s0 = (blockIdx.x & 15) << 6;
  {
    const int r = tid >> 2, cq = (tid & 3) << 4;
    const float* src = V + ((size_t)bh * SSZ + s0 + r) * DD + cq;
    *(float4*)&tile[r][cq + 0]  = *(const float4*)(src + 0);
    *(float4*)&tile[r][cq + 4]  = *(const float4*)(src + 4);
    *(float4*)&tile[r][cq + 8]  = *(const float4*)(src + 8);
    *(float4*)&tile[r][cq + 12] = *(const float4*)(src + 12);
  }
  __syncthreads();
  {
    const int d = tid >> 2, sq = (tid & 3) << 4;
    const int s1 = s0 + sq, s2 = s1 + 8;
    unsigned short* d0 = g_Vt + ((size_t)(bh * 32 + (s1 >> 5)) * DD + d) * 32 + (s1 & 31);
    unsigned short* d1 = g_Vt + ((size_t)(bh * 32 + (s2 >> 5)) * DD + d) * 32 + (s2 & 31);
    *(s16x8*)d0 = pack8f(tile[sq + 0][d], tile[sq + 1][d], tile[sq + 2][d], tile[sq + 3][d],
                         tile[sq + 4][d], tile[sq + 5][d], tile[sq + 6][d], tile[sq + 7][d]);
    *(s16x8*)d1 = pack8f(tile[sq + 8][d], tile[sq + 9][d], tile[sq + 10][d], tile[sq + 11][d],
                         tile[sq + 12][d], tile[sq + 13][d], tile[sq + 14][d], tile[sq + 15][d]);
  }
}

// ---------------- K1: p = sigmoid(Q K^T + bias) via bf16 MFMA -> g_Qb (bf16) ----------------
__global__ __launch_bounds__(256) void k_energy(const float* __restrict__ Q,
                                                const float* __restrict__ Kp,
                                                const float* __restrict__ eb) {
  const int tid = threadIdx.x, w = tid >> 6, l = tid & 63;
  const int rl = l & 15, kg = l >> 4;
  const int bh = blockIdx.x >> 6;
  const int tile = blockIdx.x & 63;
  const int m0 = (tile >> 2) << 6;
  const int n0 = (((tile & 3) << 2) + w) << 6;
  const float* qb = Q + (size_t)bh * TT * DD;
  const float* kb = Kp + (size_t)bh * SSZ * DD;

  f32x4 acc[4][4];
#pragma unroll
  for (int i = 0; i < 4; ++i)
#pragma unroll
    for (int j = 0; j < 4; ++j) acc[i][j] = (f32x4)0.0f;

#pragma unroll
  for (int ks = 0; ks < 2; ++ks) {
    const int kof = (ks << 5) + (kg << 3);
    s16x8 af[4], bf[4];
#pragma unroll
    for (int fi = 0; fi < 4; ++fi)
      af[fi] = pack8p(qb + (size_t)(m0 + fi * 16 + rl) * DD + kof);
#pragma unroll
    for (int fj = 0; fj < 4; ++fj)
      bf[fj] = pack8p(kb + (size_t)(n0 + fj * 16 + rl) * DD + kof);
#pragma unroll
    for (int fi = 0; fi < 4; ++fi)
#pragma unroll
      for (int fj = 0; fj < 4; ++fj)
        acc[fi][fj] = __builtin_amdgcn_mfma_f32_16x16x32_bf16(af[fi], bf[fj], acc[fi][fj], 0, 0, 0);
  }

  const float bias = eb[0];
  unsigned short* pb = g_Qb + (size_t)bh * TT * SSZ;
#pragma unroll
  for (int fi = 0; fi < 4; ++fi)
#pragma unroll
    for (int r = 0; r < 4; ++r) {
      const size_t rowoff = (size_t)(m0 + fi * 16 + (kg << 2) + r) * SSZ;
#pragma unroll
      for (int fj = 0; fj < 4; ++fj) {
        float x = acc[fi][fj][r] + bias;
        float s = __builtin_amdgcn_rcpf(1.0f + __expf(-x));
        pb[rowoff + n0 + fj * 16 + rl] = bfr(s);
      }
    }
}

// ---------------- K2: 4-wave s-split scan (round-15 proven version) ----------------
#define STEP(T, QS) do {                                                       \
  const int t_ = (T);                                                          \
  asm volatile("s_waitcnt vmcnt(8)" ::: "memory");                             \
  __builtin_amdgcn_sched_barrier(0);                                           \
  float fn0 = 1.0f - bfl(QS[0]);                                               \
  float fn1 = 1.0f - bfh(QS[0]);                                               \
  float fn2 = 1.0f - bfl(QS[1]);                                               \
  float fn3 = 1.0f - bfh(QS[1]);                                               \
  { int rr = t_ + 5; if (rr > TT - 1) rr = TT - 1;                             \
    QS = aload2(gqe + (size_t)rr * SSZ); }                                     \
  float ln0 = fn0, ln1 = ln0 * fn1, ln2 = ln1 * fn2, ln3 = ln2 * fn3;          \
  float An0 = ln3;                                                             \
  float An1 = An0 * f_dpp<0x111, 0xF>(An0, 1.0f);                              \
  float An2 = An1 * f_dpp<0x112, 0xF>(An1, 1.0f);                              \
  float An3 = An2 * f_dpp<0x114, 0xF>(An2, 1.0f);                              \
  float An4 = An3 * f_dpp<0x118, 0xF>(An3, 1.0f);                              \
  float An5 = An4 * f_dpp<0x142, 0xA>(An4, 1.0f);                              \
  float An6 = An5 * f_dpp<0x143, 0xC>(An5, 1.0f);                              \
  float wEn = wave_shr1(An6, 1.0f);                                            \
  float bb0 = fminf(c0  * prev0, prev0);                                       \
  float bb1 = fminf(cl0 * prev1, prev1);                                       \
  float bb2 = fminf(cl1 * prev2, prev2);                                       \
  float bb3 = fminf(cl2 * prev3, prev3);                                       \
  float Blo1 = fmaf(fc0, bb0, bb1);                                            \
  float Blo2 = fmaf(fc1, Blo1, bb2);                                           \
  float Blo3 = fmaf(fc2, Blo2, bb3);                                           \
  float B_ = fc3 * Blo3;                                                       \
  B_ = fmaf(As0, f_dpp<0x111, 0xF>(B_, 0.0f), B_);                             \
  B_ = fmaf(As1, f_dpp<0x112, 0xF>(B_, 0.0f), B_);                             \
  B_ = fmaf(As2, f_dpp<0x114, 0xF>(B_, 0.0f), B_);                             \
  B_ = fmaf(As3, f_dpp<0x118, 0xF>(B_, 0.0f), B_);                             \
  B_ = fmaf(As4, f_dpp<0x142, 0xA>(B_, 0.0f), B_);                             \
  float Bfull = fmaf(As5, f_dpp<0x143, 0xC>(B_, 0.0f), B_);                    \
  float wB = wave_shr1(Bfull, 0.0f);                                           \
  if (lane == 63) ldsAB[t_ & 1][w] = make_float2(An6, Bfull);                  \
  asm volatile("s_waitcnt lgkmcnt(0)" ::: "memory");                           \
  __builtin_amdgcn_s_barrier();                                                \
  __builtin_amdgcn_sched_barrier(0);                                           \
  float2 ab0 = ldsAB[t_ & 1][0];                                               \
  float2 ab1 = ldsAB[t_ & 1][1];                                               \
  float2 ab2 = ldsAB[t_ & 1][2];                                               \
  float Ew = 0.0f;                                                             \
  if (w == 1) Ew = ab0.y;                                                      \
  else if (w == 2) Ew = fmaf(A1g, ab0.y, ab1.y);                               \
  else if (w == 3) Ew = fmaf(A2g, fmaf(A1g, ab0.y, ab1.y), ab2.y);             \
  float El = fmaf(wE, Ew, wB);                                                 \
  float D0 = bb0 + El;                                                         \
  float D1 = fmaf(lc0, El, Blo1);                                              \
  float D2 = fmaf(lc1, El, Blo2);                                              \
  float D3 = fmaf(lc2, El, Blo3);                                              \
  float a0 = fminf(fmaf(-fc0, D0, D0), 1.0f);                                  \
  float a1 = fminf(fmaf(-fc1, D1, D1), 1.0f);                                  \
  float a2 = fminf(fmaf(-fc2, D2, D2), 1.0f);                                  \
  float a3 = fminf(fmaf(-fc3, D3, D3), 1.0f);                                  \
  prev0 = a0; prev1 = a1; prev2 = a2; prev3 = a3;                              \
  f32x4 av4; av4.x = a0; av4.y = a1; av4.z = a2; av4.w = a3;                   \
  if (tid != 255) {                                                            \
    astore(gq + (size_t)t_ * SSZ, av4);                                        \
    i32x2 pk; pk[0] = cvt_pk(a0, a1); pk[1] = cvt_pk(a2, a3);                  \
    astore2(gpb + (size_t)t_ * 32, pk);                                        \
  }                                                                            \
  float la = (a0 + a1) + (a2 + a3);                                            \
  float wsum = wscan_add(la);                                                  \
  if (lane == 63 && w < 3) ldsS[t_ & 1][w] = wsum;                             \
  if (tid == 255) {                                                            \
    if (t_ > 0) {                                                              \
      float tot = ldsS[(t_ - 1) & 1][0] + ldsS[(t_ - 1) & 1][1]                \
                + ldsS[(t_ - 1) & 1][2] + wsum_prev;                           \
      float rest = tot - pend.w;                                               \
      pend.w = 1.0f - fminf(fmaxf(rest, 0.0f), 1.0f);                          \
      astore(gq + (size_t)(t_ - 1) * SSZ, pend);                               \
      i32x2 pk2; pk2[0] = cvt_pk(pend.x, pend.y); pk2[1] = cvt_pk(pend.z, pend.w); \
      astore2(gpb + (size_t)(t_ - 1) * 32, pk2);                               \
    }                                                                          \
    pend = av4; wsum_prev = wsum;                                              \
  }                                                                            \
  fc0 = fn0; fc1 = fn1; fc2 = fn2; fc3 = fn3;                                  \
  lc0 = ln0; lc1 = ln1; lc2 = ln2;                                             \
  As0 = An0; As1 = An1; As2 = An2; As3 = An3; As4 = An4; As5 = An5;            \
  wE = wEn;                                                                    \
  float Pw_ = 1.0f;                                                            \
  if (w > 0) Pw_ = ab0.x;                                                      \
  if (w > 1) Pw_ *= ab1.x;                                                     \
  if (w > 2) Pw_ *= ab2.x;                                                     \
  c0 = (Pw_ * 1e6f) * wEn;                                                     \
  cl0 = c0 * ln0; cl1 = c0 * ln1; cl2 = c0 * ln2;                              \
  A1g = ab1.x; A2g = ab2.x;                                                    \
} while (0)

__global__ __launch_bounds__(256, 1) void k_scan(float* __restrict__ A) {
  const int b = blockIdx.x;
  const int tid = threadIdx.x;
  const int w = tid >> 6;
  const int lane = tid & 63;
  __shared__ float2 ldsAB[2][4];
  __shared__ float ldsS[2][4];

  float* gq = A + (size_t)b * TT * SSZ + ((size_t)w << 8) + ((size_t)lane << 2);
  const unsigned short* gqe = g_Qb + (size_t)b * TT * SSZ + ((size_t)w << 8) + ((size_t)lane << 2);
  // k-blocked alpha-bf16 target: s = w*256 + lane*4 -> sb = s>>5, si = s&31
  const int sb = (w << 3) + (lane >> 3);
  unsigned short* gpb = g_Pb + ((size_t)(b * 32 + sb) * TT) * 32 + ((lane & 7) << 2);

  // ring: slot k holds row r with r&3==k
  i32x2 q0 = aload2(gqe + (size_t)0 * SSZ);
  i32x2 q1 = aload2(gqe + (size_t)1 * SSZ);
  i32x2 q2 = aload2(gqe + (size_t)2 * SSZ);
  i32x2 q3 = aload2(gqe + (size_t)3 * SSZ);
  asm volatile("s_waitcnt vmcnt(0)" ::: "memory");
  __builtin_amdgcn_sched_barrier(0);

  // row-0 state
  float fc0 = 1.0f - bfl(q0[0]);
  float fc1 = 1.0f - bfh(q0[0]);
  float fc2 = 1.0f - bfl(q0[1]);
  float fc3 = 1.0f - bfh(q0[1]);
  q0 = aload2(gqe + (size_t)4 * SSZ);
  float lc0 = fc0, lc1 = lc0 * fc1, lc2 = lc1 * fc2;
  float lc3 = lc2 * fc3;
  float As0 = lc3;
  float As1 = As0 * f_dpp<0x111, 0xF>(As0, 1.0f);
  float As2 = As1 * f_dpp<0x112, 0xF>(As1, 1.0f);
  float As3 = As2 * f_dpp<0x114, 0xF>(As2, 1.0f);
  float As4 = As3 * f_dpp<0x118, 0xF>(As3, 1.0f);
  float As5 = As4 * f_dpp<0x142, 0xA>(As4, 1.0f);
  float A6  = As5 * f_dpp<0x143, 0xC>(As5, 1.0f);
  float wE = wave_shr1(A6, 1.0f);
  if (lane == 63) ldsAB[1][w] = make_float2(A6, 0.0f);
  asm volatile("s_waitcnt lgkmcnt(0)" ::: "memory");
  __builtin_amdgcn_s_barrier();
  __builtin_amdgcn_sched_barrier(0);
  float2 pab0 = ldsAB[1][0], pab1 = ldsAB[1][1], pab2 = ldsAB[1][2];
  float A1g = pab1.x, A2g = pab2.x;
  float Pw = 1.0f;
  if (w > 0) Pw = pab0.x;
  if (w > 1) Pw *= pab1.x;
  if (w > 2) Pw *= pab2.x;
  float c0 = (Pw * 1e6f) * wE;
  float cl0 = c0 * lc0, cl1 = c0 * lc1, cl2 = c0 * lc2;

  float prev0 = (tid == 0) ? 1.0f : 0.0f;
  float prev1 = 0.0f, prev2 = 0.0f, prev3 = 0.0f;
  f32x4 pend; pend.x = 0.0f; pend.y = 0.0f; pend.z = 0.0f; pend.w = 0.0f;
  float wsum_prev = 0.0f;

  for (int t0 = 0; t0 < TT; t0 += 4) {
    STEP(t0 + 0, q1);
    STEP(t0 + 1, q2);
    STEP(t0 + 2, q3);
    STEP(t0 + 3, q0);
  }

  asm volatile("s_waitcnt lgkmcnt(0)" ::: "memory");
  __builtin_amdgcn_s_barrier();
  __builtin_amdgcn_sched_barrier(0);
  if (tid == 255) {
    float tot = ldsS[(TT - 1) & 1][0] + ldsS[(TT - 1) & 1][1]
              + ldsS[(TT - 1) & 1][2] + wsum_prev;
    float rest = tot - pend.w;
    pend.w = 1.0f - fminf(fmaxf(rest, 0.0f), 1.0f);
    astore(gq + (size_t)(TT - 1) * SSZ, pend);
    i32x2 pk; pk[0] = cvt_pk(pend.x, pend.y); pk[1] = cvt_pk(pend.z, pend.w);
    astore2(gpb + (size_t)(TT - 1) * 32, pk);
  }
}

// ---------------- K3: X = alpha_bf16 @ V^T_bf16 via MFMA -> g_Xb (k-blocked) ----------------
__global__ __launch_bounds__(256) void k_av() {
  const int tid = threadIdx.x, w = tid >> 6, l = tid & 63;
  const int rl = l & 15, kg = l >> 4;
  const int gw = blockIdx.x * 4 + w;
  const int bh = gw >> 6;
  const int t0 = (gw & 63) << 4;

  // k-blocked alpha: slot j of lane (rl,kg) at kk -> alpha[t0+rl][kk*32+kg*8+j]
  const unsigned short* ab = g_Pb + ((size_t)(bh * 32) * TT + (t0 + rl)) * 32 + (kg << 3);
  // k-blocked V^T: lane (rl,kg), fj, kk -> V^T[fj*16+rl][kk*32+kg*8+j]
  const unsigned short* vb = g_Vt + ((size_t)(bh * 32) * DD + rl) * 32 + (kg << 3);

  f32x4 acc[4];
#pragma unroll
  for (int j = 0; j < 4; ++j) acc[j] = (f32x4)0.0f;

  for (int kk = 0; kk < 32; ++kk) {
    s16x8 a = *(const s16x8*)(ab + (size_t)kk * TT * 32);
#pragma unroll
    for (int fj = 0; fj < 4; ++fj) {
      s16x8 b = *(const s16x8*)(vb + ((size_t)kk * DD + fj * 16) * 32);
      acc[fj] = __builtin_amdgcn_mfma_f32_16x16x32_bf16(a, b, acc[fj], 0, 0, 0);
    }
  }

  // store into k-blocked g_Xb: element (e, m) at ((e>>5)*4096 + m)*32 + (e&31)
  const int bz = bh >> 4, hh = bh & 15;
#pragma unroll
  for (int fj = 0; fj < 4; ++fj) {
    const int e = hh * DD + fj * 16 + rl;
    const size_t ebase = ((size_t)(e >> 5) * (TT * BSZN)) * 32 + (e & 31);
#pragma unroll
    for (int r = 0; r < 4; ++r) {
      const int m = (t0 + (kg << 2) + r) * BSZN + bz;
      g_Xb[ebase + (size_t)m * 32] = bfr(acc[fj][r]);
    }
  }
}

// ---------------- K4: Out = X_bf16 @ W_bf16^T + b via MFMA (k-blocked X and W loads) ----------------
__global__ __launch_bounds__(256) void k_out(const float* __restrict__ Bb,
                                             float* __restrict__ Out) {
  const int tid = threadIdx.x, w = tid >> 6, l = tid & 63;
  const int rl = l & 15, kg = l >> 4;
  const int gw = blockIdx.x * 4 + w;
  const int m0 = (gw >> 4) << 4;
  const int n0 = (gw & 15) << 6;

  // k-blocked X: slot j at kk -> X[m0+rl][kk*32+kg*8+j]
  const unsigned short* xb = g_Xb + (size_t)(m0 + rl) * 32 + (kg << 3);
  // k-blocked W: slot j of (fj, kk) -> W[n0+fj*16+rl][kk*32+kg*8+j]
  const unsigned short* wb = g_Wb + (kg << 3);

  f32x4 acc[4];
#pragma unroll
  for (int j = 0; j < 4; ++j) acc[j] = (f32x4)0.0f;

  for (int kk = 0; kk < 32; ++kk) {
    s16x8 a = *(const s16x8*)(xb + (size_t)kk * (TT * BSZN) * 32);
#pragma unroll
    for (int fj = 0; fj < 4; ++fj) {
      s16x8 b = *(const s16x8*)(wb + ((size_t)kk * EEN + (n0 + fj * 16 + rl)) * 32);
      acc[fj] = __builtin_amdgcn_mfma_f32_16x16x32_bf16(a, b, acc[fj], 0, 0, 0);
    }
  }

#pragma unroll
  for (int fj = 0; fj < 4; ++fj) {
    const float bias = Bb[n0 + fj * 16 + rl];
#pragma unroll
    for (int r = 0; r < 4; ++r) {
      const int m = m0 + (kg << 2) + r;
      Out[(size_t)m * EEN + n0 + fj * 16 + rl] = acc[fj][r] + bias;
    }
  }
}

extern "C" void kernel_launch(void* const* d_in, const int* in_sizes, int n_in,
                              void* d_out, int out_size, void* d_ws, size_t ws_size,
                              hipStream_t stream) {
  const float* Q  = (const float*)d_in[0];
  const float* K  = (const float*)d_in[1];
  const float* V  = (const float*)d_in[2];
  const float* W  = (const float*)d_in[3];
  const float* Bb = (const float*)d_in[4];
  const float* eb = (const float*)d_in[5];
  float* Out = (float*)d_out;
  float* Alpha = Out + (size_t)TT * BSZN * EEN;  // alpha f32 output region

  k_prep_w<<<dim3(512), dim3(256), 0, stream>>>(W);
  k_prep_v<<<dim3(BHN * 16), dim3(256), 0, stream>>>(V);
  k_energy<<<dim3(BHN * 64), dim3(256), 0, stream>>>(Q, K, eb);
  k_scan<<<dim3(BHN), dim3(256), 0, stream>>>(Alpha);
  k_av<<<dim3(1024), dim3(256), 0, stream>>>();
  k_out<<<dim3(1024), dim3(256), 0, stream>>>(Bb, Out);
}

// Round 19
// 661.554 us; speedup vs baseline: 1.1725x; 1.0171x over previous
//
#include <hip/hip_runtime.h>

#define TT 1024
#define SSZ 1024
#define DD 64
#define BHN 64
#define BSZN 4
#define EEN 1024
#define EPSF 1e-6f

using f32x4 = __attribute__((ext_vector_type(4))) float;
using i32x2 = __attribute__((ext_vector_type(2))) int;
using i32x4 = __attribute__((ext_vector_type(4))) int;
using s16x8 = __attribute__((ext_vector_type(8))) short;

// static buffers (avoid ws_size assumptions)
__device__ unsigned short g_Qb[(size_t)BHN * TT * SSZ];  // bf16 p_choose, row-major [bh][t][s]
__device__ unsigned short g_Pb[(size_t)BHN * TT * SSZ];  // bf16 alpha, k-blocked [bh*32+sb][t][32]
__device__ unsigned short g_Vt[(size_t)BHN * DD * SSZ];  // bf16 V^T, k-blocked [bh*32+sb][d][32]
__device__ unsigned short g_Wb[(size_t)EEN * EEN];       // bf16 W, k-blocked [kb][n][32]
__device__ unsigned short g_Xb[(size_t)TT * BSZN * EEN]; // bf16 X, k-blocked [eb][m][32]

// ---------------- helpers ----------------
template<int CTRL, int RM>
__device__ __forceinline__ float f_dpp(float x, float ident) {
  return __builtin_bit_cast(float,
      __builtin_amdgcn_update_dpp(__builtin_bit_cast(int, ident),
                                  __builtin_bit_cast(int, x),
                                  CTRL, RM, 0xF, false));
}

__device__ __forceinline__ float wscan_add(float x) {
  x += f_dpp<0x111, 0xF>(x, 0.0f);
  x += f_dpp<0x112, 0xF>(x, 0.0f);
  x += f_dpp<0x114, 0xF>(x, 0.0f);
  x += f_dpp<0x118, 0xF>(x, 0.0f);
  x += f_dpp<0x142, 0xA>(x, 0.0f);
  x += f_dpp<0x143, 0xC>(x, 0.0f);
  return x;
}

__device__ __forceinline__ float wave_shr1(float x, float ident) {
  return f_dpp<0x138, 0xF>(x, ident);
}

__device__ __forceinline__ i32x2 aload2(const unsigned short* p) {
  i32x2 r;
  asm volatile("global_load_dwordx2 %0, %1, off" : "=v"(r) : "v"(p));
  return r;
}
__device__ __forceinline__ void astore(float* p, f32x4 v) {
  asm volatile("global_store_dwordx4 %0, %1, off" :: "v"(p), "v"(v) : "memory");
}
__device__ __forceinline__ void astore2(unsigned short* p, i32x2 v) {
  asm volatile("global_store_dwordx2 %0, %1, off" :: "v"(p), "v"(v) : "memory");
}

__device__ __forceinline__ int cvt_pk(float lo, float hi) {
  int r;
  asm("v_cvt_pk_bf16_f32 %0, %1, %2" : "=v"(r) : "v"(lo), "v"(hi));
  return r;
}
__device__ __forceinline__ unsigned short bfr(float x) {  // scalar RTNE bf16
  unsigned u = __builtin_bit_cast(unsigned, x);
  u += 0x7fffu + ((u >> 16) & 1u);
  return (unsigned short)(u >> 16);
}
__device__ __forceinline__ float bfl(int u) {  // low bf16 -> f32
  return __builtin_bit_cast(float, u << 16);
}
__device__ __forceinline__ float bfh(int u) {  // high bf16 -> f32
  return __builtin_bit_cast(float, (int)((unsigned)u & 0xffff0000u));
}
__device__ __forceinline__ s16x8 pack8p(const float* p) {  // 8 consecutive f32 -> bf16x8
  f32x4 a = *(const f32x4*)p;
  f32x4 b = *(const f32x4*)(p + 4);
  i32x4 r;
  r[0] = cvt_pk(a[0], a[1]); r[1] = cvt_pk(a[2], a[3]);
  r[2] = cvt_pk(b[0], b[1]); r[3] = cvt_pk(b[2], b[3]);
  return __builtin_bit_cast(s16x8, r);
}
__device__ __forceinline__ s16x8 pack8f(float v0, float v1, float v2, float v3,
                                        float v4, float v5, float v6, float v7) {
  i32x4 r;
  r[0] = cvt_pk(v0, v1); r[1] = cvt_pk(v2, v3);
  r[2] = cvt_pk(v4, v5); r[3] = cvt_pk(v6, v7);
  return __builtin_bit_cast(s16x8, r);
}

// ---------------- K1 (fused front): energy | V-prep | W-prep by block range ----------------
// blocks [0,4096): p = sigmoid(Q K^T + bias) -> g_Qb      (round-18 k_energy body)
// blocks [4096,5120): V -> bf16 k-blocked V^T             (round-18 k_prep_v body)
// blocks [5120,5632): W -> bf16 k-blocked [kb][n][32]     (round-18 k_prep_w body)
__global__ __launch_bounds__(256) void k_front(const float* __restrict__ Q,
                                               const float* __restrict__ Kp,
                                               const float* __restrict__ eb,
                                               const float* __restrict__ V,
                                               const float* __restrict__ W) {
  __shared__ float tile[64][65];
  const int tid = threadIdx.x;
  const int bidx = blockIdx.x;

  if (bidx < BHN * 64) {
    // ---- energy ----
    const int w = tid >> 6, l = tid & 63;
    const int rl = l & 15, kg = l >> 4;
    const int bh = bidx >> 6;
    const int t4 = bidx & 63;
    const int m0 = (t4 >> 2) << 6;
    const int n0 = (((t4 & 3) << 2) + w) << 6;
    const float* qb = Q + (size_t)bh * TT * DD;
    const float* kb = Kp + (size_t)bh * SSZ * DD;

    f32x4 acc[4][4];
#pragma unroll
    for (int i = 0; i < 4; ++i)
#pragma unroll
      for (int j = 0; j < 4; ++j) acc[i][j] = (f32x4)0.0f;

#pragma unroll
    for (int ks = 0; ks < 2; ++ks) {
      const int kof = (ks << 5) + (kg << 3);
      s16x8 af[4], bf[4];
#pragma unroll
      for (int fi = 0; fi < 4; ++fi)
        af[fi] = pack8p(qb + (size_t)(m0 + fi * 16 + rl) * DD + kof);
#pragma unroll
      for (int fj = 0; fj < 4; ++fj)
        bf[fj] = pack8p(kb + (size_t)(n0 + fj * 16 + rl) * DD + kof);
#pragma unroll
      for (int fi = 0; fi < 4; ++fi)
#pragma unroll
        for (int fj = 0; fj < 4; ++fj)
          acc[fi][fj] = __builtin_amdgcn_mfma_f32_16x16x32_bf16(af[fi], bf[fj], acc[fi][fj], 0, 0, 0);
    }

    const float bias = eb[0];
    unsigned short* pb = g_Qb + (size_t)bh * TT * SSZ;
#pragma unroll
    for (int fi = 0; fi < 4; ++fi)
#pragma unroll
      for (int r = 0; r < 4; ++r) {
        const size_t rowoff = (size_t)(m0 + fi * 16 + (kg << 2) + r) * SSZ;
#pragma unroll
        for (int fj = 0; fj < 4; ++fj) {
          float x = acc[fi][fj][r] + bias;
          float s = __builtin_amdgcn_rcpf(1.0f + __expf(-x));
          pb[rowoff + n0 + fj * 16 + rl] = bfr(s);
        }
      }
  } else if (bidx < BHN * 64 + BHN * 16) {
    // ---- V prep ----
    const int bid = bidx - BHN * 64;
    const int bh = bid >> 4;
    const int s0 = (bid & 15) << 6;
    {
      const int r = tid >> 2, cq = (tid & 3) << 4;
      const float* src = V + ((size_t)bh * SSZ + s0 + r) * DD + cq;
      *(float4*)&tile[r][cq + 0]  = *(const float4*)(src + 0);
      *(float4*)&tile[r][cq + 4]  = *(const float4*)(src + 4);
      *(float4*)&tile[r][cq + 8]  = *(const float4*)(src + 8);
      *(float4*)&tile[r][cq + 12] = *(const float4*)(src + 12);
    }
    __syncthreads();
    {
      const int d = tid >> 2, sq = (tid & 3) << 4;
      const int s1 = s0 + sq, s2 = s1 + 8;
      unsigned short* d0 = g_Vt + ((size_t)(bh * 32 + (s1 >> 5)) * DD + d) * 32 + (s1 & 31);
      unsigned short* d1 = g_Vt + ((size_t)(bh * 32 + (s2 >> 5)) * DD + d) * 32 + (s2 & 31);
      *(s16x8*)d0 = pack8f(tile[sq + 0][d], tile[sq + 1][d], tile[sq + 2][d], tile[sq + 3][d],
                           tile[sq + 4][d], tile[sq + 5][d], tile[sq + 6][d], tile[sq + 7][d]);
      *(s16x8*)d1 = pack8f(tile[sq + 8][d], tile[sq + 9][d], tile[sq + 10][d], tile[sq + 11][d],
                           tile[sq + 12][d], tile[sq + 13][d], tile[sq + 14][d], tile[sq + 15][d]);
    }
  } else {
    // ---- W prep ----
    const int bid = bidx - (BHN * 64 + BHN * 16);
    const size_t idx = ((size_t)bid * 256 + tid) * 8;
    const int n = (int)(idx >> 10);
    const int k0 = (int)(idx & 1023);
    unsigned short* dst = g_Wb + ((size_t)(k0 >> 5) * EEN + n) * 32 + (k0 & 31);
    *(s16x8*)dst = pack8p(W + idx);
  }
}

// ---------------- K2: 4-wave s-split scan (round-15 proven version) ----------------
#define STEP(T, QS) do {                                                       \
  const int t_ = (T);                                                          \
  asm volatile("s_waitcnt vmcnt(8)" ::: "memory");                             \
  __builtin_amdgcn_sched_barrier(0);                                           \
  float fn0 = 1.0f - bfl(QS[0]);                                               \
  float fn1 = 1.0f - bfh(QS[0]);                                               \
  float fn2 = 1.0f - bfl(QS[1]);                                               \
  float fn3 = 1.0f - bfh(QS[1]);                                               \
  { int rr = t_ + 5; if (rr > TT - 1) rr = TT - 1;                             \
    QS = aload2(gqe + (size_t)rr * SSZ); }                                     \
  float ln0 = fn0, ln1 = ln0 * fn1, ln2 = ln1 * fn2, ln3 = ln2 * fn3;          \
  float An0 = ln3;                                                             \
  float An1 = An0 * f_dpp<0x111, 0xF>(An0, 1.0f);                              \
  float An2 = An1 * f_dpp<0x112, 0xF>(An1, 1.0f);                              \
  float An3 = An2 * f_dpp<0x114, 0xF>(An2, 1.0f);                              \
  float An4 = An3 * f_dpp<0x118, 0xF>(An3, 1.0f);                              \
  float An5 = An4 * f_dpp<0x142, 0xA>(An4, 1.0f);                              \
  float An6 = An5 * f_dpp<0x143, 0xC>(An5, 1.0f);                              \
  float wEn = wave_shr1(An6, 1.0f);                                            \
  float bb0 = fminf(c0  * prev0, prev0);                                       \
  float bb1 = fminf(cl0 * prev1, prev1);                                       \
  float bb2 = fminf(cl1 * prev2, prev2);                                       \
  float bb3 = fminf(cl2 * prev3, prev3);                                       \
  float Blo1 = fmaf(fc0, bb0, bb1);                                            \
  float Blo2 = fmaf(fc1, Blo1, bb2);                                           \
  float Blo3 = fmaf(fc2, Blo2, bb3);                                           \
  float B_ = fc3 * Blo3;                                                       \
  B_ = fmaf(As0, f_dpp<0x111, 0xF>(B_, 0.0f), B_);                             \
  B_ = fmaf(As1, f_dpp<0x112, 0xF>(B_, 0.0f), B_);                             \
  B_ = fmaf(As2, f_dpp<0x114, 0xF>(B_, 0.0f), B_);                             \
  B_ = fmaf(As3, f_dpp<0x118, 0xF>(B_, 0.0f), B_);                             \
  B_ = fmaf(As4, f_dpp<0x142, 0xA>(B_, 0.0f), B_);                             \
  float Bfull = fmaf(As5, f_dpp<0x143, 0xC>(B_, 0.0f), B_);                    \
  float wB = wave_shr1(Bfull, 0.0f);                                           \
  if (lane == 63) ldsAB[t_ & 1][w] = make_float2(An6, Bfull);                  \
  asm volatile("s_waitcnt lgkmcnt(0)" ::: "memory");                           \
  __builtin_amdgcn_s_barrier();                                                \
  __builtin_amdgcn_sched_barrier(0);                                           \
  float2 ab0 = ldsAB[t_ & 1][0];                                               \
  float2 ab1 = ldsAB[t_ & 1][1];                                               \
  float2 ab2 = ldsAB[t_ & 1][2];                                               \
  float Ew = 0.0f;                                                             \
  if (w == 1) Ew = ab0.y;                                                      \
  else if (w == 2) Ew = fmaf(A1g, ab0.y, ab1.y);                               \
  else if (w == 3) Ew = fmaf(A2g, fmaf(A1g, ab0.y, ab1.y), ab2.y);             \
  float El = fmaf(wE, Ew, wB);                                                 \
  float D0 = bb0 + El;                                                         \
  float D1 = fmaf(lc0, El, Blo1);                                              \
  float D2 = fmaf(lc1, El, Blo2);                                              \
  float D3 = fmaf(lc2, El, Blo3);                                              \
  float a0 = fminf(fmaf(-fc0, D0, D0), 1.0f);                                  \
  float a1 = fminf(fmaf(-fc1, D1, D1), 1.0f);                                  \
  float a2 = fminf(fmaf(-fc2, D2, D2), 1.0f);                                  \
  float a3 = fminf(fmaf(-fc3, D3, D3), 1.0f);                                  \
  prev0 = a0; prev1 = a1; prev2 = a2; prev3 = a3;                              \
  f32x4 av4; av4.x = a0; av4.y = a1; av4.z = a2; av4.w = a3;                   \
  if (tid != 255) {                                                            \
    astore(gq + (size_t)t_ * SSZ, av4);                                        \
    i32x2 pk; pk[0] = cvt_pk(a0, a1); pk[1] = cvt_pk(a2, a3);                  \
    astore2(gpb + (size_t)t_ * 32, pk);                                        \
  }                                                                            \
  float la = (a0 + a1) + (a2 + a3);                                            \
  float wsum = wscan_add(la);                                                  \
  if (lane == 63 && w < 3) ldsS[t_ & 1][w] = wsum;                             \
  if (tid == 255) {                                                            \
    if (t_ > 0) {                                                              \
      float tot = ldsS[(t_ - 1) & 1][0] + ldsS[(t_ - 1) & 1][1]                \
                + ldsS[(t_ - 1) & 1][2] + wsum_prev;                           \
      float rest = tot - pend.w;                                               \
      pend.w = 1.0f - fminf(fmaxf(rest, 0.0f), 1.0f);                          \
      astore(gq + (size_t)(t_ - 1) * SSZ, pend);                               \
      i32x2 pk2; pk2[0] = cvt_pk(pend.x, pend.y); pk2[1] = cvt_pk(pend.z, pend.w); \
      astore2(gpb + (size_t)(t_ - 1) * 32, pk2);                               \
    }                                                                          \
    pend = av4; wsum_prev = wsum;                                              \
  }                                                                            \
  fc0 = fn0; fc1 = fn1; fc2 = fn2; fc3 = fn3;                                  \
  lc0 = ln0; lc1 = ln1; lc2 = ln2;                                             \
  As0 = An0; As1 = An1; As2 = An2; As3 = An3; As4 = An4; As5 = An5;            \
  wE = wEn;                                                                    \
  float Pw_ = 1.0f;                                                            \
  if (w > 0) Pw_ = ab0.x;                                                      \
  if (w > 1) Pw_ *= ab1.x;                                                     \
  if (w > 2) Pw_ *= ab2.x;                                                     \
  c0 = (Pw_ * 1e6f) * wEn;                                                     \
  cl0 = c0 * ln0; cl1 = c0 * ln1; cl2 = c0 * ln2;                              \
  A1g = ab1.x; A2g = ab2.x;                                                    \
} while (0)

__global__ __launch_bounds__(256, 1) void k_scan(float* __restrict__ A) {
  const int b = blockIdx.x;
  const int tid = threadIdx.x;
  const int w = tid >> 6;
  const int lane = tid & 63;
  __shared__ float2 ldsAB[2][4];
  __shared__ float ldsS[2][4];

  float* gq = A + (size_t)b * TT * SSZ + ((size_t)w << 8) + ((size_t)lane << 2);
  const unsigned short* gqe = g_Qb + (size_t)b * TT * SSZ + ((size_t)w << 8) + ((size_t)lane << 2);
  // k-blocked alpha-bf16 target: s = w*256 + lane*4 -> sb = s>>5, si = s&31
  const int sb = (w << 3) + (lane >> 3);
  unsigned short* gpb = g_Pb + ((size_t)(b * 32 + sb) * TT) * 32 + ((lane & 7) << 2);

  // ring: slot k holds row r with r&3==k
  i32x2 q0 = aload2(gqe + (size_t)0 * SSZ);
  i32x2 q1 = aload2(gqe + (size_t)1 * SSZ);
  i32x2 q2 = aload2(gqe + (size_t)2 * SSZ);
  i32x2 q3 = aload2(gqe + (size_t)3 * SSZ);
  asm volatile("s_waitcnt vmcnt(0)" ::: "memory");
  __builtin_amdgcn_sched_barrier(0);

  // row-0 state
  float fc0 = 1.0f - bfl(q0[0]);
  float fc1 = 1.0f - bfh(q0[0]);
  float fc2 = 1.0f - bfl(q0[1]);
  float fc3 = 1.0f - bfh(q0[1]);
  q0 = aload2(gqe + (size_t)4 * SSZ);
  float lc0 = fc0, lc1 = lc0 * fc1, lc2 = lc1 * fc2;
  float lc3 = lc2 * fc3;
  float As0 = lc3;
  float As1 = As0 * f_dpp<0x111, 0xF>(As0, 1.0f);
  float As2 = As1 * f_dpp<0x112, 0xF>(As1, 1.0f);
  float As3 = As2 * f_dpp<0x114, 0xF>(As2, 1.0f);
  float As4 = As3 * f_dpp<0x118, 0xF>(As3, 1.0f);
  float As5 = As4 * f_dpp<0x142, 0xA>(As4, 1.0f);
  float A6  = As5 * f_dpp<0x143, 0xC>(As5, 1.0f);
  float wE = wave_shr1(A6, 1.0f);
  if (lane == 63) ldsAB[1][w] = make_float2(A6, 0.0f);
  asm volatile("s_waitcnt lgkmcnt(0)" ::: "memory");
  __builtin_amdgcn_s_barrier();
  __builtin_amdgcn_sched_barrier(0);
  float2 pab0 = ldsAB[1][0], pab1 = ldsAB[1][1], pab2 = ldsAB[1][2];
  float A1g = pab1.x, A2g = pab2.x;
  float Pw = 1.0f;
  if (w > 0) Pw = pab0.x;
  if (w > 1) Pw *= pab1.x;
  if (w > 2) Pw *= pab2.x;
  float c0 = (Pw * 1e6f) * wE;
  float cl0 = c0 * lc0, cl1 = c0 * lc1, cl2 = c0 * lc2;

  float prev0 = (tid == 0) ? 1.0f : 0.0f;
  float prev1 = 0.0f, prev2 = 0.0f, prev3 = 0.0f;
  f32x4 pend; pend.x = 0.0f; pend.y = 0.0f; pend.z = 0.0f; pend.w = 0.0f;
  float wsum_prev = 0.0f;

  for (int t0 = 0; t0 < TT; t0 += 4) {
    STEP(t0 + 0, q1);
    STEP(t0 + 1, q2);
    STEP(t0 + 2, q3);
    STEP(t0 + 3, q0);
  }

  asm volatile("s_waitcnt lgkmcnt(0)" ::: "memory");
  __builtin_amdgcn_s_barrier();
  __builtin_amdgcn_sched_barrier(0);
  if (tid == 255) {
    float tot = ldsS[(TT - 1) & 1][0] + ldsS[(TT - 1) & 1][1]
              + ldsS[(TT - 1) & 1][2] + wsum_prev;
    float rest = tot - pend.w;
    pend.w = 1.0f - fminf(fmaxf(rest, 0.0f), 1.0f);
    astore(gq + (size_t)(TT - 1) * SSZ, pend);
    i32x2 pk; pk[0] = cvt_pk(pend.x, pend.y); pk[1] = cvt_pk(pend.z, pend.w);
    astore2(gpb + (size_t)(TT - 1) * 32, pk);
  }
}

// ---------------- K3: X = alpha_bf16 @ V^T_bf16 via MFMA -> g_Xb (k-blocked) ----------------
__global__ __launch_bounds__(256) void k_av() {
  const int tid = threadIdx.x, w = tid >> 6, l = tid & 63;
  const int rl = l & 15, kg = l >> 4;
  const int gw = blockIdx.x * 4 + w;
  const int bh = gw >> 6;
  const int t0 = (gw & 63) << 4;

  // k-blocked alpha: slot j of lane (rl,kg) at kk -> alpha[t0+rl][kk*32+kg*8+j]
  const unsigned short* ab = g_Pb + ((size_t)(bh * 32) * TT + (t0 + rl)) * 32 + (kg << 3);
  // k-blocked V^T: lane (rl,kg), fj, kk -> V^T[fj*16+rl][kk*32+kg*8+j]
  const unsigned short* vb = g_Vt + ((size_t)(bh * 32) * DD + rl) * 32 + (kg << 3);

  f32x4 acc[4];
#pragma unroll
  for (int j = 0; j < 4; ++j) acc[j] = (f32x4)0.0f;

  for (int kk = 0; kk < 32; ++kk) {
    s16x8 a = *(const s16x8*)(ab + (size_t)kk * TT * 32);
#pragma unroll
    for (int fj = 0; fj < 4; ++fj) {
      s16x8 b = *(const s16x8*)(vb + ((size_t)kk * DD + fj * 16) * 32);
      acc[fj] = __builtin_amdgcn_mfma_f32_16x16x32_bf16(a, b, acc[fj], 0, 0, 0);
    }
  }

  // store into k-blocked g_Xb: element (e, m) at ((e>>5)*4096 + m)*32 + (e&31)
  const int bz = bh >> 4, hh = bh & 15;
#pragma unroll
  for (int fj = 0; fj < 4; ++fj) {
    const int e = hh * DD + fj * 16 + rl;
    const size_t ebase = ((size_t)(e >> 5) * (TT * BSZN)) * 32 + (e & 31);
#pragma unroll
    for (int r = 0; r < 4; ++r) {
      const int m = (t0 + (kg << 2) + r) * BSZN + bz;
      g_Xb[ebase + (size_t)m * 32] = bfr(acc[fj][r]);
    }
  }
}

// ---------------- K4: Out = X_bf16 @ W_bf16^T + b via MFMA (k-blocked X and W loads) ----------------
__global__ __launch_bounds__(256) void k_out(const float* __restrict__ Bb,
                                             float* __restrict__ Out) {
  const int tid = threadIdx.x, w = tid >> 6, l = tid & 63;
  const int rl = l & 15, kg = l >> 4;
  const int gw = blockIdx.x * 4 + w;
  const int m0 = (gw >> 4) << 4;
  const int n0 = (gw & 15) << 6;

  // k-blocked X: slot j at kk -> X[m0+rl][kk*32+kg*8+j]
  const unsigned short* xb = g_Xb + (size_t)(m0 + rl) * 32 + (kg << 3);
  // k-blocked W: slot j of (fj, kk) -> W[n0+fj*16+rl][kk*32+kg*8+j]
  const unsigned short* wb = g_Wb + (kg << 3);

  f32x4 acc[4];
#pragma unroll
  for (int j = 0; j < 4; ++j) acc[j] = (f32x4)0.0f;

  for (int kk = 0; kk < 32; ++kk) {
    s16x8 a = *(const s16x8*)(xb + (size_t)kk * (TT * BSZN) * 32);
#pragma unroll
    for (int fj = 0; fj < 4; ++fj) {
      s16x8 b = *(const s16x8*)(wb + ((size_t)kk * EEN + (n0 + fj * 16 + rl)) * 32);
      acc[fj] = __builtin_amdgcn_mfma_f32_16x16x32_bf16(a, b, acc[fj], 0, 0, 0);
    }
  }

#pragma unroll
  for (int fj = 0; fj < 4; ++fj) {
    const float bias = Bb[n0 + fj * 16 + rl];
#pragma unroll
    for (int r = 0; r < 4; ++r) {
      const int m = m0 + (kg << 2) + r;
      Out[(size_t)m * EEN + n0 + fj * 16 + rl] = acc[fj][r] + bias;
    }
  }
}

extern "C" void kernel_launch(void* const* d_in, const int* in_sizes, int n_in,
                              void* d_out, int out_size, void* d_ws, size_t ws_size,
                              hipStream_t stream) {
  const float* Q  = (const float*)d_in[0];
  const float* K  = (const float*)d_in[1];
  const float* V  = (const float*)d_in[2];
  const float* W  = (const float*)d_in[3];
  const float* Bb = (const float*)d_in[4];
  const float* eb = (const float*)d_in[5];
  float* Out = (float*)d_out;
  float* Alpha = Out + (size_t)TT * BSZN * EEN;  // alpha f32 output region

  k_front<<<dim3(BHN * 64 + BHN * 16 + 512), dim3(256), 0, stream>>>(Q, K, eb, V, W);
  k_scan<<<dim3(BHN), dim3(256), 0, stream>>>(Alpha);
  k_av<<<dim3(1024), dim3(256), 0, stream>>>();
  k_out<<<dim3(1024), dim3(256), 0, stream>>>(Bb, Out);
}